// Round 3
// baseline (165.498 us; speedup 1.0000x reference)
//
#include <hip/hip_runtime.h>

// LSTM: B=4096, T=256, I=8, H=32, O=1, fp32 in/out, bf16 MFMA compute.
// R8 = R7 structure with 8-row tiles and 2 independent blocks per CU:
// 512 blocks x 8 waves (launch_bounds(512,4) -> 2 blocks co-resident/CU).
// The per-step chain (barrier -> ds_read h -> MFMA -> act chain -> ds_write
// -> barrier) idles ~60% of cycles when one lockstep block owns the CU
// (R7: 700 cyc/step, VALUBusy 35%, MfmaUtil 8.6%). Two blocks with
// INDEPENDENT barriers interleave: one block's issue fills the other's
// latency chain. Each wave keeps the R7 j-split: wave w owns hidden
// j = 4w + q via weight-row permutation fr -> n = 32*(fr&3) + 4w + (fr>>2)
// (weights are the MFMA FIRST operand); lane (q,L) accum reg r = gate r at
// (m=L, j=4w+q). Batch lanes L>=8 are finite duplicates of L&7 (same x,
// same init) -> harmless, no extra numerics.
// x staged in LDS as bf16 in two 128-step chunks (zero global ops in the
// steady-state loop). XSTRIDE=72 shorts: 16B-aligned b128 rows, broadcast
// read touches all 32 banks exactly once. Gate-g rows pre-scaled by
// 2*log2e (others log2e): 5 exp2 + 3 rcp per value.

#define T_LEN   256
#define HALF_T  128
#define XSTRIDE 72    // shorts per timestep row (8 rows x 8 bf16 + 8 pad)
#define LOG2E   1.4426950408889634f

typedef short bf16x8 __attribute__((ext_vector_type(8)));
typedef float f32x4  __attribute__((ext_vector_type(4)));
typedef unsigned u32x4 __attribute__((ext_vector_type(4)));

static __device__ inline short f2bf_rne(float f) {          // one-time (weights)
    union { float f; unsigned u; } v; v.f = f;
    unsigned u = v.u;
    return (short)((u + 0x7FFFu + ((u >> 16) & 1u)) >> 16);
}
static __device__ inline short f2bf_fast(float f) {         // round-half-up
    union { float f; unsigned u; } v; v.f = f;
    return (short)((v.u + 0x8000u) >> 16);
}
static __device__ inline unsigned pack_bf2(float a, float b) {  // low=a, high=b
    union { float f; unsigned u; } x, y; x.f = a; y.f = b;
    return ((x.u + 0x8000u) >> 16) | ((y.u + 0x8000u) & 0xFFFF0000u);
}
static __device__ inline float bf2f(short s) {
    union { unsigned u; float f; } v;
    v.u = ((unsigned)(unsigned short)s) << 16;
    return v.f;
}

__global__ __launch_bounds__(512, 4) void lstm_kernel(
    const float* __restrict__ x, const float* __restrict__ W_ih,
    const float* __restrict__ W_hh, const float* __restrict__ b_ih,
    const float* __restrict__ b_hh, const float* __restrict__ W_out,
    const float* __restrict__ b_out, float* __restrict__ out)
{
    // x chunk: [t_local(0..127)][L(0..7)][8] bf16, 16B-aligned rows.
    __shared__ __attribute__((aligned(16))) short xl[HALF_T * XSTRIDE];
    // h double buffer: [buf][m(0..15)][k(0..31)] bf16, row stride 40 shorts
    // (rows 8..15 are the duplicate-batch lanes; finite, never read back).
    __shared__ __attribute__((aligned(16))) short h_lds[2][16 * 40];

    const int tid  = threadIdx.x;
    const int w    = tid >> 6;        // wave 0..7 -> owns j = 4w + q
    const int lane = tid & 63;
    const int L    = lane & 15;       // batch row within tile / frag row
    const int q    = lane >> 4;       // quad
    const int row0 = blockIdx.x * 8;  // 8 valid batch rows per block
    const float4* xv = (const float4*)x;

    // ---- one-time: weight fragments (FIRST-operand layout [row=L][k=8q+j]) ----
    // row fr=L holds W row n = 32*(L&3) + 4w + (L>>2); gate = L&3,
    // scaled by log2e (gate-g rows: 2*log2e, folding tanh's factor 2).
    const int   n  = 32 * (L & 3) + 4 * w + (L >> 2);
    const float sc = ((L & 3) == 2 ? 2.f * LOG2E : LOG2E);
    bf16x8 whh_f, wih_f = (bf16x8){0,0,0,0,0,0,0,0};
    {
        const float* src = W_hh + n * 32 + q * 8;
#pragma unroll
        for (int j = 0; j < 8; ++j) whh_f[j] = f2bf_rne(src[j] * sc);
        if (q == 0) {                              // only k=0..7 exist (I=8)
            const float* s2 = W_ih + n * 8;
#pragma unroll
            for (int j = 0; j < 8; ++j) wih_f[j] = f2bf_rne(s2[j] * sc);
        }
    }
    // bias in C-layout: reg r -> row fr=4q+r -> n_r = 32r + 4w + q
    f32x4 bias;
#pragma unroll
    for (int r = 0; r < 4; ++r) {
        const int   nr = 32 * r + 4 * w + q;
        const float sr = (r == 2 ? 2.f * LOG2E : LOG2E);
        bias[r] = (b_ih[nr] + b_hh[nr]) * sr;
    }

    // zero h(0) buffer
    for (int i = tid; i < 16 * 40; i += 512) h_lds[0][i] = 0;

    // ---- stage chunk 0 (t in [0,128)) into xl ----
    // idx = tid + 512*it: L2 = idx>>7 (0..7), tl = idx&127; 32 B/lane coalesced.
#pragma unroll
    for (int it = 0; it < 2; ++it) {
        const int idx = tid + (it << 9);
        const int L2  = idx >> 7;
        const int tl  = idx & (HALF_T - 1);
        const float4* srcp = xv + ((size_t)(row0 + L2) * T_LEN + tl) * 2;
        const float4 a = srcp[0], b = srcp[1];
        u32x4 u;
        u[0] = pack_bf2(a.x, a.y); u[1] = pack_bf2(a.z, a.w);
        u[2] = pack_bf2(b.x, b.y); u[3] = pack_bf2(b.z, b.w);
        *(u32x4*)(&xl[tl * XSTRIDE + L2 * 8]) = u;
    }
    __syncthreads();

    // zx(0) from x(0)
    f32x4 zx;
    {
        const bf16x8 xf0 = *(const bf16x8*)(&xl[(L & 7) * 8]);
        zx = __builtin_amdgcn_mfma_f32_16x16x32_bf16(wih_f, xf0, bias, 0, 0, 0);
    }

    float c = 0.f;
    const int hw_off = 4 * w + q;      // this lane's j

#pragma unroll 2
    for (int t = 0; t < T_LEN; ++t) {
        if (t == HALF_T - 1) {
            // chunk-0 fully consumed (last read was x(127) during t=126).
#pragma unroll
            for (int it = 0; it < 2; ++it) {
                const int idx = tid + (it << 9);
                const int L2  = idx >> 7;
                const int tl  = idx & (HALF_T - 1);
                const float4* srcp = xv + ((size_t)(row0 + L2) * T_LEN + HALF_T + tl) * 2;
                const float4 a = srcp[0], b = srcp[1];
                u32x4 u;
                u[0] = pack_bf2(a.x, a.y); u[1] = pack_bf2(a.z, a.w);
                u[2] = pack_bf2(b.x, b.y); u[3] = pack_bf2(b.z, b.w);
                *(u32x4*)(&xl[tl * XSTRIDE + L2 * 8]) = u;
            }
            __syncthreads();   // one-time vm drain; loop stays vm-free
        }

        const int par = t & 1, nxt = par ^ 1;

        // h(t) fragment [n=L][k=8q+j]
        const bf16x8 hfrag = *(const bf16x8*)(&h_lds[par][L * 40 + q * 8]);
        // x(t+1) fragment (broadcast read; q>0 lanes hit zeroed wih rows)
        int tn = t + 1; if (tn >= T_LEN) tn = T_LEN - 1;
        const bf16x8 xfrag = *(const bf16x8*)(&xl[(tn & (HALF_T - 1)) * XSTRIDE + (L & 7) * 8]);

        // recurrence MFMA (chain) + next-step zx (off-chain)
        const f32x4 acc = __builtin_amdgcn_mfma_f32_16x16x32_bf16(whh_f, hfrag, zx, 0, 0, 0);
        zx = __builtin_amdgcn_mfma_f32_16x16x32_bf16(wih_f, xfrag, bias, 0, 0, 0);

        // activation: regs r = (i, f, g2, o); g rows pre-doubled.
        // sig(a)*tanh(b) = (1-eb)*rcp((1+ea)(1+eb)); only c-exp clamped.
        {
            const float ei = __builtin_amdgcn_exp2f(-acc[0]);
            const float ef = __builtin_amdgcn_exp2f(-acc[1]);
            const float eg = __builtin_amdgcn_exp2f(-acc[2]);
            const float eo = __builtin_amdgcn_exp2f(-acc[3]);
            const float fv = __builtin_amdgcn_rcpf(1.f + ef);
            const float ig = (1.f - eg) * __builtin_amdgcn_rcpf((1.f + ei) * (1.f + eg));
            c = fmaf(fv, c, ig);
            const float ec = __builtin_amdgcn_exp2f(fminf(c * (-2.f * LOG2E), 40.f));
            const float hv = (1.f - ec) * __builtin_amdgcn_rcpf((1.f + eo) * (1.f + ec));
            h_lds[nxt][L * 40 + hw_off] = f2bf_fast(hv);
        }

        __syncthreads();   // LDS-only drain: no global ops in flight
    }

    // h(T) lives in buf[(255+1)&1] = buf[0]; only the 8 valid rows written out.
    if (tid < 8) {
        float s = b_out[0];
#pragma unroll
        for (int k = 0; k < 32; ++k) s = fmaf(bf2f(h_lds[0][tid * 40 + k]), W_out[k], s);
        out[row0 + tid] = s;
    }
}

extern "C" void kernel_launch(void* const* d_in, const int* in_sizes, int n_in,
                              void* d_out, int out_size, void* d_ws, size_t ws_size,
                              hipStream_t stream) {
    const float* x     = (const float*)d_in[0];
    const float* W_ih  = (const float*)d_in[1];
    const float* W_hh  = (const float*)d_in[2];
    const float* b_ih  = (const float*)d_in[3];
    const float* b_hh  = (const float*)d_in[4];
    const float* W_out = (const float*)d_in[5];
    const float* b_out = (const float*)d_in[6];
    float* out = (float*)d_out;

    const int B = in_sizes[0] / (T_LEN * 8);  // 4096
    const int tiles = B / 8;                  // 512 blocks, two per CU
    lstm_kernel<<<tiles, 512, 0, stream>>>(x, W_ih, W_hh, b_ih, b_hh, W_out, b_out, out);
}

// Round 4
// 150.796 us; speedup vs baseline: 1.0975x; 1.0975x over previous
//
#include <hip/hip_runtime.h>

// LSTM: B=4096, T=256, I=8, H=32, O=1, fp32 in/out, bf16 MFMA compute.
// R9: 4-wave tiles, 2 j's per lane. R8 post-mortem: wall = chain x 256 steps;
// co-resident blocks cannot compress the serial chain (R8: +36% from
// contention). So shrink the chain: 256 blocks x 256 threads (1/CU, 4 waves
// on 4 SIMDs). Wave s owns j in [8s, 8s+8): lane (q,L) owns j = 8s+2q+{0,1}
// via TWO MFMAs (m=0,1) with row-perm n(cr) = 32*(cr&3) + 8s + 2*(cr>>2) + m
// (weights are the MFMA FIRST operand). All 4 gates of both j's land in the
// lane's two f32x4 accs -> c/h update fully in-register; h exchange is ONE
// aligned ds_write_b32 (2-way bank pattern, free) + 4-wave barrier + one
// b128 read (broadcast-paired, ~free). Act work: 16 trans/wave/step on 4
// separate SIMDs (own trans units). x staged in LDS as bf16, two 128-step
// chunks, XOR-swizzled XSTRIDE=128: all b128 ops 16B-aligned, staging writes
// provably conflict-free, reads 2-way (free). Gate-g rows pre-scaled by
// 2*log2e (others log2e): 5 exp2 + 3 rcp per (j,batch) value.

#define T_LEN   256
#define HALF_T  128
#define LOG2E   1.4426950408889634f

typedef short bf16x8 __attribute__((ext_vector_type(8)));
typedef float f32x4  __attribute__((ext_vector_type(4)));
typedef unsigned u32x4 __attribute__((ext_vector_type(4)));

static __device__ inline short f2bf_rne(float f) {          // one-time (weights)
    union { float f; unsigned u; } v; v.f = f;
    unsigned u = v.u;
    return (short)((u + 0x7FFFu + ((u >> 16) & 1u)) >> 16);
}
static __device__ inline unsigned pack_bf2(float a, float b) {  // low=a, high=b
    union { float f; unsigned u; } x, y; x.f = a; y.f = b;
    return ((x.u + 0x8000u) >> 16) | ((y.u + 0x8000u) & 0xFFFF0000u);
}

__global__ __launch_bounds__(256, 1) void lstm_kernel(
    const float* __restrict__ x, const float* __restrict__ W_ih,
    const float* __restrict__ W_hh, const float* __restrict__ b_ih,
    const float* __restrict__ b_hh, const float* __restrict__ W_out,
    const float* __restrict__ b_out, float* __restrict__ out)
{
    // x chunk: [t_local][swizzled L slot][8] bf16. Slot for (t,L) is
    // (L ^ (t&7)): write side (tl varies per lane) covers all 32 banks per
    // 8 lanes; read side (t uniform) is 16 distinct 16B rows = 2-way, free.
    __shared__ __attribute__((aligned(16))) short xl[HALF_T * 128];   // 32 KB
    // h double buffer: [buf][L(0..15)][k(0..31)] bf16, row stride 40 shorts.
    __shared__ __attribute__((aligned(16))) short h_lds[2][16 * 40];  // 2.5 KB

    const int tid  = threadIdx.x;
    const int s    = tid >> 6;        // wave 0..3 -> owns j in [8s, 8s+8)
    const int lane = tid & 63;
    const int L    = lane & 15;       // batch row within tile / frag row
    const int q    = lane >> 4;       // quad
    const int row0 = blockIdx.x * 16;
    const float4* xv = (const float4*)x;

    // ---- one-time: weight fragments, FIRST-operand layout [row=L][k=8q+kk].
    // MFMA m (m=0,1): A row fr holds W row n = 32*(fr&3) + 8s + 2*(fr>>2) + m,
    // gate = fr&3, scaled by log2e (gate-g rows: 2*log2e folds tanh's 2).
    bf16x8 whh[2], wih[2];
    f32x4  bias[2];
    const float scL = ((L & 3) == 2 ? 2.f * LOG2E : LOG2E);
#pragma unroll
    for (int m = 0; m < 2; ++m) {
        const int n = 32 * (L & 3) + 8 * s + 2 * (L >> 2) + m;
        const float* src = W_hh + n * 32 + q * 8;
#pragma unroll
        for (int j = 0; j < 8; ++j) whh[m][j] = f2bf_rne(src[j] * scL);
        wih[m] = (bf16x8){0,0,0,0,0,0,0,0};
        if (q == 0) {                              // only k=0..7 exist (I=8)
            const float* s2 = W_ih + n * 8;
#pragma unroll
            for (int j = 0; j < 8; ++j) wih[m][j] = f2bf_rne(s2[j] * scL);
        }
        // bias in C-layout: reg r -> gate r of j = 8s+2q+m -> n_r = 32r + j
#pragma unroll
        for (int r = 0; r < 4; ++r) {
            const int   nr = 32 * r + 8 * s + 2 * q + m;
            const float sr = (r == 2 ? 2.f * LOG2E : LOG2E);
            bias[m][r] = (b_ih[nr] + b_hh[nr]) * sr;
        }
    }
    const int   hoff = 8 * s + 2 * q;            // this lane's j (even)
    const float Wo0 = W_out[hoff], Wo1 = W_out[hoff + 1];

    // ---- stage chunk 0 (t in [0,128)) into xl ----
    // idx = tid + 256k: L2 = idx>>7, tl = idx&127 -> 64 consecutive tl per
    // wave = 2KB coalesced global; LDS write banks: 4*((L2^(tl&7))&7) over
    // 8 consecutive lanes covers all 32 banks exactly once (optimal).
#pragma unroll
    for (int k = 0; k < 8; ++k) {
        const int idx = tid + (k << 8);
        const int L2  = idx >> 7;
        const int tl  = idx & (HALF_T - 1);
        const float4* srcp = xv + ((size_t)(row0 + L2) * T_LEN + tl) * 2;
        const float4 a = srcp[0], b = srcp[1];
        u32x4 u;
        u[0] = pack_bf2(a.x, a.y); u[1] = pack_bf2(a.z, a.w);
        u[2] = pack_bf2(b.x, b.y); u[3] = pack_bf2(b.z, b.w);
        *(u32x4*)(&xl[tl * 128 + ((L2 ^ (tl & 7)) << 3)]) = u;
    }
    __syncthreads();

    // zx(0) from x(0): slot (L ^ 0) = L
    f32x4 zx0, zx1;
    {
        const bf16x8 xf0 = *(const bf16x8*)(&xl[L * 8]);
        zx0 = __builtin_amdgcn_mfma_f32_16x16x32_bf16(wih[0], xf0, bias[0], 0, 0, 0);
        zx1 = __builtin_amdgcn_mfma_f32_16x16x32_bf16(wih[1], xf0, bias[1], 0, 0, 0);
    }

    bf16x8 hfrag = (bf16x8){0,0,0,0,0,0,0,0};    // h(0) = 0
    float c0 = 0.f, c1 = 0.f, h0v = 0.f, h1v = 0.f;

#pragma unroll 2
    for (int t = 0; t < T_LEN; ++t) {
        if (t == HALF_T - 1) {
            // chunk-0 fully consumed (last read was x(127) during t=126,
            // ordered by that iteration's end barrier).
#pragma unroll
            for (int k = 0; k < 8; ++k) {
                const int idx = tid + (k << 8);
                const int L2  = idx >> 7;
                const int tl  = idx & (HALF_T - 1);
                const float4* srcp = xv + ((size_t)(row0 + L2) * T_LEN + HALF_T + tl) * 2;
                const float4 a = srcp[0], b = srcp[1];
                u32x4 u;
                u[0] = pack_bf2(a.x, a.y); u[1] = pack_bf2(a.z, a.w);
                u[2] = pack_bf2(b.x, b.y); u[3] = pack_bf2(b.z, b.w);
                *(u32x4*)(&xl[tl * 128 + ((L2 ^ (tl & 7)) << 3)]) = u;
            }
            __syncthreads();   // one-time vm drain; loop stays vm-free
        }

        // z(t) = W_hh h(t) + zx(t): two chained MFMAs (independent of each other)
        const f32x4 a0 = __builtin_amdgcn_mfma_f32_16x16x32_bf16(whh[0], hfrag, zx0, 0, 0, 0);
        const f32x4 a1 = __builtin_amdgcn_mfma_f32_16x16x32_bf16(whh[1], hfrag, zx1, 0, 0, 0);

        // x(t+1) fragment (broadcast read; q>0 lanes rely on zeroed wih rows)
        int tn = t + 1; if (tn >= T_LEN) tn = T_LEN - 1;
        const bf16x8 xfrag = *(const bf16x8*)(
            &xl[(tn & (HALF_T - 1)) * 128 + ((L ^ (tn & 7)) << 3)]);
        zx0 = __builtin_amdgcn_mfma_f32_16x16x32_bf16(wih[0], xfrag, bias[0], 0, 0, 0);
        zx1 = __builtin_amdgcn_mfma_f32_16x16x32_bf16(wih[1], xfrag, bias[1], 0, 0, 0);

        // activation x2: regs r = (i, f, g2, o); g rows pre-doubled.
        // sig(a)*tanh(b) = (1-eb)*rcp((1+ea)(1+eb)); only c-exp clamped.
        {
            const float ei = __builtin_amdgcn_exp2f(-a0[0]);
            const float ef = __builtin_amdgcn_exp2f(-a0[1]);
            const float eg = __builtin_amdgcn_exp2f(-a0[2]);
            const float eo = __builtin_amdgcn_exp2f(-a0[3]);
            const float fv = __builtin_amdgcn_rcpf(1.f + ef);
            const float ig = (1.f - eg) * __builtin_amdgcn_rcpf((1.f + ei) * (1.f + eg));
            c0 = fmaf(fv, c0, ig);
            const float ec = __builtin_amdgcn_exp2f(fminf(c0 * (-2.f * LOG2E), 40.f));
            h0v = (1.f - ec) * __builtin_amdgcn_rcpf((1.f + eo) * (1.f + ec));
        }
        {
            const float ei = __builtin_amdgcn_exp2f(-a1[0]);
            const float ef = __builtin_amdgcn_exp2f(-a1[1]);
            const float eg = __builtin_amdgcn_exp2f(-a1[2]);
            const float eo = __builtin_amdgcn_exp2f(-a1[3]);
            const float fv = __builtin_amdgcn_rcpf(1.f + ef);
            const float ig = (1.f - eg) * __builtin_amdgcn_rcpf((1.f + ei) * (1.f + eg));
            c1 = fmaf(fv, c1, ig);
            const float ec = __builtin_amdgcn_exp2f(fminf(c1 * (-2.f * LOG2E), 40.f));
            h1v = (1.f - ec) * __builtin_amdgcn_rcpf((1.f + eo) * (1.f + ec));
        }

        if (t != T_LEN - 1) {          // block-uniform; last h stays in regs
            const int nxt = (t & 1) ^ 1;
            // one aligned b32 write: dword bank (L*20 + 4s + q)&31 = 2-way, free
            *(unsigned*)(&h_lds[nxt][L * 40 + hoff]) = pack_bf2(h0v, h1v);
            __syncthreads();           // 4-wave barrier, LDS-only drain
            hfrag = *(const bf16x8*)(&h_lds[nxt][L * 40 + 8 * q]);
        }
    }

    // ---- epilogue: out = h(T) . W_out + b ----
    float partial = fmaf(h0v, Wo0, h1v * Wo1);
    partial += __shfl_xor(partial, 16, 64);      // sum over q (same L)
    partial += __shfl_xor(partial, 32, 64);
    float* po = (float*)h_lds;                   // buf0: no pending ops race
    if (lane < 16) po[s * 16 + lane] = partial;
    __syncthreads();
    if (tid < 16)
        out[row0 + tid] = po[tid] + po[16 + tid] + po[32 + tid] + po[48 + tid]
                        + b_out[0];
}

extern "C" void kernel_launch(void* const* d_in, const int* in_sizes, int n_in,
                              void* d_out, int out_size, void* d_ws, size_t ws_size,
                              hipStream_t stream) {
    const float* x     = (const float*)d_in[0];
    const float* W_ih  = (const float*)d_in[1];
    const float* W_hh  = (const float*)d_in[2];
    const float* b_ih  = (const float*)d_in[3];
    const float* b_hh  = (const float*)d_in[4];
    const float* W_out = (const float*)d_in[5];
    const float* b_out = (const float*)d_in[6];
    float* out = (float*)d_out;

    const int B = in_sizes[0] / (T_LEN * 8);  // 4096
    const int tiles = B / 16;                 // 256 blocks, one per CU
    lstm_kernel<<<tiles, 256, 0, stream>>>(x, W_ih, W_hh, b_ih, b_hh, W_out, b_out, out);
}